// Round 15
// baseline (411.314 us; speedup 1.0000x reference)
//
#include <hip/hip_runtime.h>
#include <math.h>

#define D 1024
#define H 16
#define DK 64
#define SQ 1024
#define NB 8
#define NROW (NB*SQ)   // 8192

typedef __attribute__((ext_vector_type(8))) short bf16x8;
typedef __attribute__((ext_vector_type(4))) float f32x4;

__device__ __forceinline__ ushort f2bf(float x){
    unsigned u = __builtin_bit_cast(unsigned, x);
    u += 0x7FFFu + ((u >> 16) & 1u);
    return (ushort)(u >> 16);
}
__device__ __forceinline__ float bf2f(ushort u){
    return __builtin_bit_cast(float, (unsigned)u << 16);
}

__device__ __forceinline__ f32x4 mfma16(bf16x8 a, bf16x8 b, f32x4 c){
    return __builtin_amdgcn_mfma_f32_16x16x32_bf16(a, b, c, 0, 0, 0);
}

__device__ __forceinline__ void gload16(const void* g, void* l){
    __builtin_amdgcn_global_load_lds(
        (const __attribute__((address_space(1))) unsigned int*)g,
        (__attribute__((address_space(3))) unsigned int*)l, 16, 0, 0);
}

__device__ __forceinline__ bf16x8 gld8(const ushort* p){
    return __builtin_bit_cast(bf16x8, *(const uint4*)p);
}

// custom e3m5 8-bit float, positive-only, range [2^-4, 16): byte = (u>>18)-3936
__device__ __forceinline__ unsigned q8(float x){
    unsigned u = __builtin_bit_cast(unsigned, x);
    u += 0x1FFFFu + ((u >> 18) & 1u);          // RNE into 5-bit mantissa
    return ((u >> 18) - 3936u) & 0xFFu;
}
__device__ __forceinline__ float dq8(unsigned v){
    return __builtin_bit_cast(float, ((v & 0xFFu) + 3936u) << 18);
}

// shared fragment read for [R][64] bf16 tiles with chunk^=(row&7) swizzle
__device__ __forceinline__ bf16x8 frag_ld(const ushort* lds, int row, int chunk)
{
    uint4 v = ((const uint4*)lds)[row*8 + (chunk ^ (row & 7))];
    return __builtin_bit_cast(bf16x8, v);
}

// ---------------------------------------------------------------------------
// Fused fp32 -> bf16 conversion: x (4096 blocks) then Wq,Wk,Wv,Wo (512 each).
// ---------------------------------------------------------------------------
__global__ __launch_bounds__(256)
void cvt_all(const float* __restrict__ x,
             const float* __restrict__ Wq, const float* __restrict__ Wk,
             const float* __restrict__ Wv, const float* __restrict__ Wo,
             ushort* __restrict__ xb, ushort* __restrict__ wb_)
{
    const int bid = blockIdx.x;
    const float* s; ushort* d; size_t off;
    if (bid < 4096) { s = x; d = xb; off = (size_t)bid * 2048; }
    else {
        int r = bid - 4096;
        int wsel = r >> 9;
        if      (wsel == 0) s = Wq;
        else if (wsel == 1) s = Wk;
        else if (wsel == 2) s = Wv;
        else                s = Wo;
        d = wb_ + (size_t)wsel * 1048576;
        off = (size_t)(r & 511) * 2048;
    }
    size_t i = off + (size_t)threadIdx.x * 8;
    float4 a = *(const float4*)(s + i);
    float4 b = *(const float4*)(s + i + 4);
    ushort tmp[8] = {f2bf(a.x),f2bf(a.y),f2bf(a.z),f2bf(a.w),
                     f2bf(b.x),f2bf(b.y),f2bf(b.z),f2bf(b.w)};
    *(uint4*)(d + i) = *(uint4*)tmp;
}

// ---------------------------------------------------------------------------
// bf16 MFMA GEMM, BK=64: 128x128 tile, 4 waves, 32 MFMA per barrier pair.
// ---------------------------------------------------------------------------
__device__ __forceinline__ void stage_g64(const ushort* __restrict__ g, int ldg,
                                          ushort* lds, int t)
{
#pragma unroll
    for (int i = 0; i < 4; ++i){
        int c = i*256 + t;              // 0..1023
        int row = c >> 3, sc = c & 7;
        int gch = sc ^ (row & 7);
        gload16(g + (size_t)row*ldg + gch*8, lds + c*8);
    }
}

// Fused QKV projection: W packed [3072][1024]. grid 1536 blocks 1D,
// chunked XCD swizzle: each XCD owns 8 complete A-panels (24 blocks each).
__global__ __launch_bounds__(256)
void gemm_qkv(const ushort* __restrict__ A, const ushort* __restrict__ Wp,
              const float* __restrict__ bq, const float* __restrict__ bk,
              const float* __restrict__ bv,
              ushort* __restrict__ Qb, ushort* __restrict__ Kb,
              ushort* __restrict__ Vtb)
{
    __shared__ ushort As[8192];   // 16KB
    __shared__ ushort Bs[8192];
    const int t = threadIdx.x, lane = t & 63, w = t >> 6;
    const int wr = w >> 1, wc = w & 1, lr = lane & 15, kg = lane >> 4;
    const int swz = (blockIdx.x & 7)*192 + (blockIdx.x >> 3);
    const int bx = swz % 24, by = swz / 24;
    const int i0 = by * 128, j0 = bx * 128;
    const int section = bx >> 3;                 // 0=Q 1=K 2=V
    const ushort* Ab = A  + (size_t)i0 * 1024;
    const ushort* Wb = Wp + (size_t)j0 * 1024;
    const float* bias = (section == 0) ? bq : (section == 1) ? bk : bv;
    ushort* outp      = (section == 0) ? Qb : (section == 1) ? Kb : Vtb;

    f32x4 acc[4][4];
#pragma unroll
    for (int m = 0; m < 4; ++m)
#pragma unroll
        for (int n = 0; n < 4; ++n) acc[m][n] = (f32x4){0.f,0.f,0.f,0.f};

    for (int k0 = 0; k0 < 1024; k0 += 64){
        __syncthreads();
        stage_g64(Ab + k0, 1024, As, t);
        stage_g64(Wb + k0, 1024, Bs, t);
        __syncthreads();
#pragma unroll
        for (int ks = 0; ks < 2; ++ks){
            bf16x8 af[4], bfr[4];
#pragma unroll
            for (int m = 0; m < 4; ++m) af[m]  = frag_ld(As, wr*64 + m*16 + lr, ks*4 + kg);
#pragma unroll
            for (int n = 0; n < 4; ++n) bfr[n] = frag_ld(Bs, wc*64 + n*16 + lr, ks*4 + kg);
#pragma unroll
            for (int m = 0; m < 4; ++m)
#pragma unroll
                for (int n = 0; n < 4; ++n)
                    acc[m][n] = mfma16(af[m], bfr[n], acc[m][n]);
        }
    }

#pragma unroll
    for (int m = 0; m < 4; ++m){
        int rt = i0 + wr*64 + m*16 + kg*4;
#pragma unroll
        for (int n = 0; n < 4; ++n){
            int jc = ((j0 + wc*64 + n*16 + lr) & 1023);
            float bj = bias[jc];
            int hh = jc >> 6, dd = jc & 63;
#pragma unroll
            for (int j = 0; j < 4; ++j){
                int i = rt + j;
                int b = i >> 10, s = i & 1023;
                float v = acc[m][n][j] + bj;
                size_t idx = (section < 2)
                    ? ((((size_t)b*H + hh)*SQ + s)*DK + dd)
                    : ((((size_t)b*H + hh)*DK + dd)*SQ + s);
                outp[idx] = f2bf(v);
            }
        }
    }
}

// Output projection: fp32 out + residual. 1D grid 512, chunked XCD swizzle.
__global__ __launch_bounds__(256)
void gemm_o(const ushort* __restrict__ A, const ushort* __restrict__ W,
            const float* __restrict__ bias, const float* __restrict__ resid,
            float* __restrict__ out)
{
    __shared__ ushort As[8192];
    __shared__ ushort Bs[8192];
    const int t = threadIdx.x, lane = t & 63, w = t >> 6;
    const int wr = w >> 1, wc = w & 1, lr = lane & 15, kg = lane >> 4;
    const int swz = (blockIdx.x & 7)*64 + (blockIdx.x >> 3);
    const int bx = swz & 7, by = swz >> 3;
    const int i0 = by * 128, j0 = bx * 128;
    const ushort* Ab = A + (size_t)i0 * 1024;
    const ushort* Wb = W + (size_t)j0 * 1024;

    f32x4 acc[4][4];
#pragma unroll
    for (int m = 0; m < 4; ++m)
#pragma unroll
        for (int n = 0; n < 4; ++n) acc[m][n] = (f32x4){0.f,0.f,0.f,0.f};

    for (int k0 = 0; k0 < 1024; k0 += 64){
        __syncthreads();
        stage_g64(Ab + k0, 1024, As, t);
        stage_g64(Wb + k0, 1024, Bs, t);
        __syncthreads();
#pragma unroll
        for (int ks = 0; ks < 2; ++ks){
            bf16x8 af[4], bfr[4];
#pragma unroll
            for (int m = 0; m < 4; ++m) af[m]  = frag_ld(As, wr*64 + m*16 + lr, ks*4 + kg);
#pragma unroll
            for (int n = 0; n < 4; ++n) bfr[n] = frag_ld(Bs, wc*64 + n*16 + lr, ks*4 + kg);
#pragma unroll
            for (int m = 0; m < 4; ++m)
#pragma unroll
                for (int n = 0; n < 4; ++n)
                    acc[m][n] = mfma16(af[m], bfr[n], acc[m][n]);
        }
    }

#pragma unroll
    for (int m = 0; m < 4; ++m){
        int rt = i0 + wr*64 + m*16 + kg*4;
#pragma unroll
        for (int n = 0; n < 4; ++n){
            int ct = j0 + wc*64 + n*16 + lr;
            float bj = bias[ct];
#pragma unroll
            for (int j = 0; j < 4; ++j){
                int i = rt + j;
                out[(size_t)i*1024 + ct] = acc[m][n][j] + bj + resid[(size_t)i*1024 + ct];
            }
        }
    }
}

// ---------------------------------------------------------------------------
// Flash attention v13: SINGLE pass (r8's v9 resurrected WITHOUT the register
// cap). Block = 64 q rows, 4 waves x 16 rows, LDS 40KB. Per tile: stage K+V
// dbuf, QK^T, e=exp2 (unnormalized), lsum accum, e->bf16 P LDS (PV frags),
// e->e3m5 byte in 64 statically-indexed VGPRs. No global stores in loop.
// After loop: shfl-reduce invl, ctx=acc*invl, then barrier-free NONTEMPORAL
// scalar writeout (16-lane groups cover dense 64B segments). NO
// __launch_bounds__ min-wave cap (r8's spill cause).
// ---------------------------------------------------------------------------
__device__ __forceinline__ void stage64x64(const ushort* __restrict__ g, int ldg,
                                           ushort* lds, int t)
{
#pragma unroll
    for (int i = 0; i < 2; ++i){
        int c = i*256 + t;
        int row = c >> 3, sc = c & 7;
        int gch = sc ^ (row & 7);
        gload16(g + (size_t)row*ldg + gch*8, lds + c*8);
    }
}

__global__ __launch_bounds__(256)
void attn_v13(const ushort* __restrict__ Q, const ushort* __restrict__ K,
              const ushort* __restrict__ Vt, float* __restrict__ attn_out,
              ushort* __restrict__ ctx)
{
    __shared__ ushort KV[2][8192];   // [buf][ K 4096 | V 4096 ] ushorts
    __shared__ ushort Ps[4][1024];   // per-wave 16x64 unnormalized e (bf16)

    const int t    = threadIdx.x;
    const int lane = t & 63;
    const int w    = t >> 6;
    const int lr   = lane & 15, kg = lane >> 4;
    const int bid  = blockIdx.x;
    const int qt   = bid >> 7, bh = bid & 127;
    const int b    = bh >> 4, hh = bh & 15;
    const size_t base = (size_t)bh * SQ * DK;

    bf16x8 qf[2];
    {
        const ushort* qrow = Q + base + (size_t)(qt*64 + w*16 + lr) * DK + kg*8;
        qf[0] = gld8(qrow);
        qf[1] = gld8(qrow + 32);
    }

    const float CEXP = 0.18033688011112042f;   // log2(e)/8

    float lsum[4] = {0.f, 0.f, 0.f, 0.f};
    f32x4 acc_o[4];
#pragma unroll
    for (int n = 0; n < 4; ++n) acc_o[n] = (f32x4){0.f,0.f,0.f,0.f};
    unsigned ereg[16][4];            // e3m5-packed e values, [kt][n]

    ushort* pw = &Ps[w][0];

    stage64x64(K  + base, DK, KV[0],        t);
    stage64x64(Vt + base, SQ, KV[0] + 4096, t);

#pragma unroll
    for (int kt = 0; kt < 16; ++kt) {
        const int cur = kt & 1;
        __syncthreads();   // staging of KV[cur] drained; all waves off KV[cur^1]
        if (kt < 15) {
            stage64x64(K  + base + (size_t)(kt+1)*64*DK, DK, KV[cur^1],        t);
            stage64x64(Vt + base + (size_t)(kt+1)*64,    SQ, KV[cur^1] + 4096, t);
        }
        const ushort* Ks = KV[cur];
        const ushort* Vs = KV[cur] + 4096;

        f32x4 sc[4];
#pragma unroll
        for (int n = 0; n < 4; ++n) {
            f32x4 z = {0.f,0.f,0.f,0.f};
            z = mfma16(qf[0], frag_ld(Ks, n*16+lr, kg),   z);
            z = mfma16(qf[1], frag_ld(Ks, n*16+lr, 4+kg), z);
            sc[n] = z;
        }
#pragma unroll
        for (int n = 0; n < 4; ++n) {
            float e0 = exp2f(sc[n][0] * CEXP);
            float e1 = exp2f(sc[n][1] * CEXP);
            float e2 = exp2f(sc[n][2] * CEXP);
            float e3 = exp2f(sc[n][3] * CEXP);
            lsum[0] += e0; lsum[1] += e1; lsum[2] += e2; lsum[3] += e3;
            ereg[kt][n] = q8(e0) | (q8(e1)<<8) | (q8(e2)<<16) | (q8(e3)<<24);
            const int col = n*16 + lr;
            { int row = kg*4 + 0; pw[row*64 + ((col>>3) ^ (row&7))*8 + (col&7)] = f2bf(e0); }
            { int row = kg*4 + 1; pw[row*64 + ((col>>3) ^ (row&7))*8 + (col&7)] = f2bf(e1); }
            { int row = kg*4 + 2; pw[row*64 + ((col>>3) ^ (row&7))*8 + (col&7)] = f2bf(e2); }
            { int row = kg*4 + 3; pw[row*64 + ((col>>3) ^ (row&7))*8 + (col&7)] = f2bf(e3); }
        }
        bf16x8 a0 = frag_ld(pw, lr, kg);
        bf16x8 a1 = frag_ld(pw, lr, 4+kg);
#pragma unroll
        for (int n = 0; n < 4; ++n) {
            acc_o[n] = mfma16(a0, frag_ld(Vs, n*16+lr, kg),   acc_o[n]);
            acc_o[n] = mfma16(a1, frag_ld(Vs, n*16+lr, 4+kg), acc_o[n]);
        }
    }

    // row sums: reduce across the 16 lanes sharing kg
    float invl[4];
#pragma unroll
    for (int r = 0; r < 4; ++r) {
        float s = lsum[r];
#pragma unroll
        for (int msk = 1; msk < 16; msk <<= 1) s += __shfl_xor(s, msk, 64);
        invl[r] = 1.0f / s;
    }

    // ctx write [B,S,D] bf16 (normalize here)
    ushort* cp = ctx + ((size_t)b*SQ + (size_t)qt*64 + w*16)*D + hh*DK;
#pragma unroll
    for (int n = 0; n < 4; ++n)
#pragma unroll
        for (int r = 0; r < 4; ++r)
            cp[(size_t)(kg*4+r)*D + n*16 + lr] = f2bf(acc_o[n][r] * invl[r]);

    // attn writeout from registers: dequant * invl, nontemporal, no barriers.
    float* ap0 = attn_out + ((size_t)bh*SQ + (size_t)qt*64 + w*16)*SQ;
#pragma unroll
    for (int kt = 0; kt < 16; ++kt) {
#pragma unroll
        for (int n = 0; n < 4; ++n) {
            unsigned pk = ereg[kt][n];
#pragma unroll
            for (int r = 0; r < 4; ++r) {
                float e = dq8(pk >> (8*r));
                __builtin_nontemporal_store(e * invl[r],
                    ap0 + (size_t)(kg*4+r)*SQ + kt*64 + n*16 + lr);
            }
        }
    }
}

// ---------------------------------------------------------------------------
// LayerNorm: wave-per-row (4 rows/block), shfl-only, no LDS/barriers,
// nontemporal y store.
// ---------------------------------------------------------------------------
__global__ __launch_bounds__(256)
void ln_k(const float* __restrict__ hbuf, const float* __restrict__ gamma,
          const float* __restrict__ beta, float* __restrict__ y)
{
    const int t = threadIdx.x;
    const int lane = t & 63;
    const int row = blockIdx.x*4 + (t >> 6);
    const f32x4* hr = (const f32x4*)(hbuf + (size_t)row * D);
    f32x4 v[4];
    float s = 0.f, sq = 0.f;
#pragma unroll
    for (int l = 0; l < 4; ++l) {
        v[l] = hr[lane + l*64];
        s  += v[l][0] + v[l][1] + v[l][2] + v[l][3];
        sq += v[l][0]*v[l][0] + v[l][1]*v[l][1] + v[l][2]*v[l][2] + v[l][3]*v[l][3];
    }
#pragma unroll
    for (int o = 32; o >= 1; o >>= 1) {
        s  += __shfl_xor(s, o, 64);
        sq += __shfl_xor(sq, o, 64);
    }
    float mu   = s * (1.0f/1024.0f);
    float var  = sq * (1.0f/1024.0f) - mu*mu;
    float rstd = rsqrtf(var + 1e-5f);
    f32x4* yp = (f32x4*)(y + (size_t)row * D);
    const f32x4* gp = (const f32x4*)gamma;
    const f32x4* bp = (const f32x4*)beta;
#pragma unroll
    for (int l = 0; l < 4; ++l) {
        f32x4 g = gp[lane + l*64], be = bp[lane + l*64];
        f32x4 o;
        o[0] = (v[l][0]-mu)*rstd*g[0] + be[0];
        o[1] = (v[l][1]-mu)*rstd*g[1] + be[1];
        o[2] = (v[l][2]-mu)*rstd*g[2] + be[2];
        o[3] = (v[l][3]-mu)*rstd*g[3] + be[3];
        __builtin_nontemporal_store(o, yp + lane + l*64);
    }
}

// ---------------------------------------------------------------------------
extern "C" void kernel_launch(void* const* d_in, const int* in_sizes, int n_in,
                              void* d_out, int out_size, void* d_ws, size_t ws_size,
                              hipStream_t stream)
{
    const float* x     = (const float*)d_in[0];
    const float* Wq    = (const float*)d_in[1];
    const float* bq    = (const float*)d_in[2];
    const float* Wk    = (const float*)d_in[3];
    const float* bk    = (const float*)d_in[4];
    const float* Wv    = (const float*)d_in[5];
    const float* bv    = (const float*)d_in[6];
    const float* Wo    = (const float*)d_in[7];
    const float* bo    = (const float*)d_in[8];
    const float* gamma = (const float*)d_in[9];
    const float* beta  = (const float*)d_in[10];

    float* y    = (float*)d_out;                     // [8,1024,1024]
    float* attn = (float*)d_out + (size_t)NROW * D;  // [8,16,1024,1024]

    const size_t SZ  = (size_t)NROW * D;             // 8M elements
    const size_t WSZ = (size_t)D * D;                // 1M elements
    ushort* ws   = (ushort*)d_ws;
    ushort* xb   = ws;                 // [8192][1024] bf16
    ushort* Wpk  = xb  + SZ;           // packed Wq|Wk|Wv [3072][1024] + Wo
    ushort* Wob  = Wpk + 3*WSZ;
    ushort* Qb   = Wob + WSZ;          // [B,H,S,DK] bf16
    ushort* Kb   = Qb  + SZ;           // [B,H,S,DK] bf16
    ushort* Vtb  = Kb  + SZ;           // [B,H,DK,SQ] bf16
    ushort* Cb   = Vtb + SZ;           // ctx [B,S,D] bf16
    float*  Hb   = (float*)(Cb + SZ);  // [8192][1024] fp32

    cvt_all<<<6144, 256, 0, stream>>>(x, Wq, Wk, Wv, Wo, xb, Wpk);

    gemm_qkv<<<1536, 256, 0, stream>>>(xb, Wpk, bq, bk, bv, Qb, Kb, Vtb);

    attn_v13<<<2048, 256, 0, stream>>>(Qb, Kb, Vtb, attn, Cb);

    gemm_o<<<512, 256, 0, stream>>>(Cb, Wob, bo, x, Hb);

    ln_k<<<2048, 256, 0, stream>>>(Hb, gamma, beta, y);
}

// Round 16
// 317.174 us; speedup vs baseline: 1.2968x; 1.2968x over previous
//
#include <hip/hip_runtime.h>
#include <math.h>

#define D 1024
#define H 16
#define DK 64
#define SQ 1024
#define NB 8
#define NROW (NB*SQ)   // 8192

typedef __attribute__((ext_vector_type(8))) short bf16x8;
typedef __attribute__((ext_vector_type(4))) float f32x4;

__device__ __forceinline__ ushort f2bf(float x){
    unsigned u = __builtin_bit_cast(unsigned, x);
    u += 0x7FFFu + ((u >> 16) & 1u);
    return (ushort)(u >> 16);
}
__device__ __forceinline__ float bf2f(ushort u){
    return __builtin_bit_cast(float, (unsigned)u << 16);
}

__device__ __forceinline__ f32x4 mfma16(bf16x8 a, bf16x8 b, f32x4 c){
    return __builtin_amdgcn_mfma_f32_16x16x32_bf16(a, b, c, 0, 0, 0);
}

__device__ __forceinline__ void gload16(const void* g, void* l){
    __builtin_amdgcn_global_load_lds(
        (const __attribute__((address_space(1))) unsigned int*)g,
        (__attribute__((address_space(3))) unsigned int*)l, 16, 0, 0);
}

__device__ __forceinline__ bf16x8 gld8(const ushort* p){
    return __builtin_bit_cast(bf16x8, *(const uint4*)p);
}

// shared fragment read for [R][64] bf16 tiles with chunk^=(row&7) swizzle
__device__ __forceinline__ bf16x8 frag_ld(const ushort* lds, int row, int chunk)
{
    uint4 v = ((const uint4*)lds)[row*8 + (chunk ^ (row & 7))];
    return __builtin_bit_cast(bf16x8, v);
}

// ---------------------------------------------------------------------------
// Fused fp32 -> bf16 conversion: x (4096 blocks) then Wq,Wk,Wv,Wo (512 each).
// ---------------------------------------------------------------------------
__global__ __launch_bounds__(256)
void cvt_all(const float* __restrict__ x,
             const float* __restrict__ Wq, const float* __restrict__ Wk,
             const float* __restrict__ Wv, const float* __restrict__ Wo,
             ushort* __restrict__ xb, ushort* __restrict__ wb_)
{
    const int bid = blockIdx.x;
    const float* s; ushort* d; size_t off;
    if (bid < 4096) { s = x; d = xb; off = (size_t)bid * 2048; }
    else {
        int r = bid - 4096;
        int wsel = r >> 9;
        if      (wsel == 0) s = Wq;
        else if (wsel == 1) s = Wk;
        else if (wsel == 2) s = Wv;
        else                s = Wo;
        d = wb_ + (size_t)wsel * 1048576;
        off = (size_t)(r & 511) * 2048;
    }
    size_t i = off + (size_t)threadIdx.x * 8;
    float4 a = *(const float4*)(s + i);
    float4 b = *(const float4*)(s + i + 4);
    ushort tmp[8] = {f2bf(a.x),f2bf(a.y),f2bf(a.z),f2bf(a.w),
                     f2bf(b.x),f2bf(b.y),f2bf(b.z),f2bf(b.w)};
    *(uint4*)(d + i) = *(uint4*)tmp;
}

// ---------------------------------------------------------------------------
// bf16 MFMA GEMM, BK=64: 128x128 tile, 4 waves, 32 MFMA per barrier pair.
// ---------------------------------------------------------------------------
__device__ __forceinline__ void stage_g64(const ushort* __restrict__ g, int ldg,
                                          ushort* lds, int t)
{
#pragma unroll
    for (int i = 0; i < 4; ++i){
        int c = i*256 + t;              // 0..1023
        int row = c >> 3, sc = c & 7;
        int gch = sc ^ (row & 7);
        gload16(g + (size_t)row*ldg + gch*8, lds + c*8);
    }
}

// Fused QKV projection: W packed [3072][1024]. grid 1536 blocks 1D,
// chunked XCD swizzle: each XCD owns 8 complete A-panels (24 blocks each).
__global__ __launch_bounds__(256)
void gemm_qkv(const ushort* __restrict__ A, const ushort* __restrict__ Wp,
              const float* __restrict__ bq, const float* __restrict__ bk,
              const float* __restrict__ bv,
              ushort* __restrict__ Qb, ushort* __restrict__ Kb,
              ushort* __restrict__ Vtb)
{
    __shared__ ushort As[8192];   // 16KB
    __shared__ ushort Bs[8192];
    const int t = threadIdx.x, lane = t & 63, w = t >> 6;
    const int wr = w >> 1, wc = w & 1, lr = lane & 15, kg = lane >> 4;
    const int swz = (blockIdx.x & 7)*192 + (blockIdx.x >> 3);
    const int bx = swz % 24, by = swz / 24;
    const int i0 = by * 128, j0 = bx * 128;
    const int section = bx >> 3;                 // 0=Q 1=K 2=V
    const ushort* Ab = A  + (size_t)i0 * 1024;
    const ushort* Wb = Wp + (size_t)j0 * 1024;
    const float* bias = (section == 0) ? bq : (section == 1) ? bk : bv;
    ushort* outp      = (section == 0) ? Qb : (section == 1) ? Kb : Vtb;

    f32x4 acc[4][4];
#pragma unroll
    for (int m = 0; m < 4; ++m)
#pragma unroll
        for (int n = 0; n < 4; ++n) acc[m][n] = (f32x4){0.f,0.f,0.f,0.f};

    for (int k0 = 0; k0 < 1024; k0 += 64){
        __syncthreads();
        stage_g64(Ab + k0, 1024, As, t);
        stage_g64(Wb + k0, 1024, Bs, t);
        __syncthreads();
#pragma unroll
        for (int ks = 0; ks < 2; ++ks){
            bf16x8 af[4], bfr[4];
#pragma unroll
            for (int m = 0; m < 4; ++m) af[m]  = frag_ld(As, wr*64 + m*16 + lr, ks*4 + kg);
#pragma unroll
            for (int n = 0; n < 4; ++n) bfr[n] = frag_ld(Bs, wc*64 + n*16 + lr, ks*4 + kg);
#pragma unroll
            for (int m = 0; m < 4; ++m)
#pragma unroll
                for (int n = 0; n < 4; ++n)
                    acc[m][n] = mfma16(af[m], bfr[n], acc[m][n]);
        }
    }

#pragma unroll
    for (int m = 0; m < 4; ++m){
        int rt = i0 + wr*64 + m*16 + kg*4;
#pragma unroll
        for (int n = 0; n < 4; ++n){
            int jc = ((j0 + wc*64 + n*16 + lr) & 1023);
            float bj = bias[jc];
            int hh = jc >> 6, dd = jc & 63;
#pragma unroll
            for (int j = 0; j < 4; ++j){
                int i = rt + j;
                int b = i >> 10, s = i & 1023;
                float v = acc[m][n][j] + bj;
                size_t idx = (section < 2)
                    ? ((((size_t)b*H + hh)*SQ + s)*DK + dd)
                    : ((((size_t)b*H + hh)*DK + dd)*SQ + s);
                outp[idx] = f2bf(v);
            }
        }
    }
}

// Output projection: fp32 out + residual. 1D grid 512, chunked XCD swizzle.
__global__ __launch_bounds__(256)
void gemm_o(const ushort* __restrict__ A, const ushort* __restrict__ W,
            const float* __restrict__ bias, const float* __restrict__ resid,
            float* __restrict__ out)
{
    __shared__ ushort As[8192];
    __shared__ ushort Bs[8192];
    const int t = threadIdx.x, lane = t & 63, w = t >> 6;
    const int wr = w >> 1, wc = w & 1, lr = lane & 15, kg = lane >> 4;
    const int swz = (blockIdx.x & 7)*64 + (blockIdx.x >> 3);
    const int bx = swz & 7, by = swz >> 3;
    const int i0 = by * 128, j0 = bx * 128;
    const ushort* Ab = A + (size_t)i0 * 1024;
    const ushort* Wb = W + (size_t)j0 * 1024;

    f32x4 acc[4][4];
#pragma unroll
    for (int m = 0; m < 4; ++m)
#pragma unroll
        for (int n = 0; n < 4; ++n) acc[m][n] = (f32x4){0.f,0.f,0.f,0.f};

    for (int k0 = 0; k0 < 1024; k0 += 64){
        __syncthreads();
        stage_g64(Ab + k0, 1024, As, t);
        stage_g64(Wb + k0, 1024, Bs, t);
        __syncthreads();
#pragma unroll
        for (int ks = 0; ks < 2; ++ks){
            bf16x8 af[4], bfr[4];
#pragma unroll
            for (int m = 0; m < 4; ++m) af[m]  = frag_ld(As, wr*64 + m*16 + lr, ks*4 + kg);
#pragma unroll
            for (int n = 0; n < 4; ++n) bfr[n] = frag_ld(Bs, wc*64 + n*16 + lr, ks*4 + kg);
#pragma unroll
            for (int m = 0; m < 4; ++m)
#pragma unroll
                for (int n = 0; n < 4; ++n)
                    acc[m][n] = mfma16(af[m], bfr[n], acc[m][n]);
        }
    }

#pragma unroll
    for (int m = 0; m < 4; ++m){
        int rt = i0 + wr*64 + m*16 + kg*4;
#pragma unroll
        for (int n = 0; n < 4; ++n){
            int ct = j0 + wc*64 + n*16 + lr;
            float bj = bias[ct];
#pragma unroll
            for (int j = 0; j < 4; ++j){
                int i = rt + j;
                out[(size_t)i*1024 + ct] = acc[m][n][j] + bj + resid[(size_t)i*1024 + ct];
            }
        }
    }
}

// ---------------------------------------------------------------------------
// Flash attention v11 (r13 best): two-pass no-max, KV dbuf, counted-vmcnt
// pass-2 barriers, NONTEMPORAL float4 attn stores. + setprio around MFMA.
// ---------------------------------------------------------------------------
__device__ __forceinline__ void stage64x64(const ushort* __restrict__ g, int ldg,
                                           ushort* lds, int t)
{
#pragma unroll
    for (int i = 0; i < 2; ++i){
        int c = i*256 + t;
        int row = c >> 3, sc = c & 7;
        int gch = sc ^ (row & 7);
        gload16(g + (size_t)row*ldg + gch*8, lds + c*8);
    }
}

__global__ __launch_bounds__(256)
void attn_v11(const ushort* __restrict__ Q, const ushort* __restrict__ K,
              const ushort* __restrict__ Vt, float* __restrict__ attn_out,
              ushort* __restrict__ ctx)
{
    __shared__ ushort KV[2][8192];   // [buf][ K 4096 | V 4096 ] ushorts
    __shared__ ushort Ps[4][1024];   // per-wave 16x64 normalized P (bf16)

    const int t    = threadIdx.x;
    const int lane = t & 63;
    const int w    = t >> 6;
    const int lr   = lane & 15, kg = lane >> 4;
    const int bid  = blockIdx.x;
    const int qt   = bid >> 7, bh = bid & 127;
    const int b    = bh >> 4, hh = bh & 15;
    const size_t base = (size_t)bh * SQ * DK;

    bf16x8 qf[2];
    {
        const ushort* qrow = Q + base + (size_t)(qt*64 + w*16 + lr) * DK + kg*8;
        qf[0] = gld8(qrow);
        qf[1] = gld8(qrow + 32);
    }

    const float CEXP = 0.18033688011112042f;   // log2(e)/8

    // ---- pass 1: row sums ----
    float lsum[4] = {0.f, 0.f, 0.f, 0.f};
    stage64x64(K + base, DK, KV[0], t);
    for (int kt = 0; kt < 16; ++kt) {
        const int cur = kt & 1;
        __syncthreads();
        if (kt < 15)
            stage64x64(K + base + (size_t)(kt+1)*64*DK, DK, KV[cur^1], t);
        const ushort* Ks = KV[cur];
        __builtin_amdgcn_s_setprio(1);
#pragma unroll
        for (int n = 0; n < 4; ++n) {
            f32x4 z = {0.f,0.f,0.f,0.f};
            z = mfma16(qf[0], frag_ld(Ks, n*16+lr, kg),   z);
            z = mfma16(qf[1], frag_ld(Ks, n*16+lr, 4+kg), z);
#pragma unroll
            for (int r = 0; r < 4; ++r)
                lsum[r] += exp2f(z[r] * CEXP);
        }
        __builtin_amdgcn_s_setprio(0);
    }
    float invl[4];
#pragma unroll
    for (int r = 0; r < 4; ++r) {
        float s = lsum[r];
#pragma unroll
        for (int msk = 1; msk < 16; msk <<= 1) s += __shfl_xor(s, msk, 64);
        invl[r] = 1.0f / s;
    }

    // ---- pass 2: recompute, write normalized P (nontemporal), PV ----
    f32x4 acc_o[4];
#pragma unroll
    for (int n = 0; n < 4; ++n) acc_o[n] = (f32x4){0.f,0.f,0.f,0.f};

    float* ap0 = attn_out + ((size_t)bh*SQ + (size_t)qt*64 + w*16)*SQ;
    ushort* pw = &Ps[w][0];

    stage64x64(K  + base, DK, KV[0],        t);
    stage64x64(Vt + base, SQ, KV[0] + 4096, t);
    asm volatile("s_waitcnt vmcnt(0) lgkmcnt(0)" ::: "memory");
    __builtin_amdgcn_s_barrier();
    __builtin_amdgcn_sched_barrier(0);

    for (int kt = 0; kt < 16; ++kt) {
        const int cur = kt & 1;
        if (kt < 15) {
            stage64x64(K  + base + (size_t)(kt+1)*64*DK, DK, KV[cur^1],        t);
            stage64x64(Vt + base + (size_t)(kt+1)*64,    SQ, KV[cur^1] + 4096, t);
        }
        const ushort* Ks = KV[cur];
        const ushort* Vs = KV[cur] + 4096;

        f32x4 sc[4];
        __builtin_amdgcn_s_setprio(1);
#pragma unroll
        for (int n = 0; n < 4; ++n) {
            f32x4 z = {0.f,0.f,0.f,0.f};
            z = mfma16(qf[0], frag_ld(Ks, n*16+lr, kg),   z);
            z = mfma16(qf[1], frag_ld(Ks, n*16+lr, 4+kg), z);
            sc[n] = z;
        }
        __builtin_amdgcn_s_setprio(0);
#pragma unroll
        for (int n = 0; n < 4; ++n) {
#pragma unroll
            for (int r = 0; r < 4; ++r) {
                float p = exp2f(sc[n][r] * CEXP) * invl[r];
                int row = kg*4 + r, col = n*16 + lr;
                pw[row*64 + ((col>>3) ^ (row&7))*8 + (col&7)] = f2bf(p);
            }
        }
        bf16x8 a0 = frag_ld(pw, lr, kg);
        bf16x8 a1 = frag_ld(pw, lr, 4+kg);
        __builtin_amdgcn_s_setprio(1);
#pragma unroll
        for (int n = 0; n < 4; ++n) {
            acc_o[n] = mfma16(a0, frag_ld(Vs, n*16+lr, kg),   acc_o[n]);
            acc_o[n] = mfma16(a1, frag_ld(Vs, n*16+lr, 4+kg), acc_o[n]);
        }
        __builtin_amdgcn_s_setprio(0);
        // nontemporal f32x4 attn writeout (bypass L2 allocation)
#pragma unroll
        for (int rr = 0; rr < 4; ++rr) {
            int row = kg*4 + rr;
            int cidx = row*64 + ((lr>>1) ^ (row&7))*8 + (lr&1)*4;
            uint2 pk = *(const uint2*)(pw + cidx);
            f32x4 o;
            o[0] = bf2f((ushort)(pk.x & 0xFFFF));
            o[1] = bf2f((ushort)(pk.x >> 16));
            o[2] = bf2f((ushort)(pk.y & 0xFFFF));
            o[3] = bf2f((ushort)(pk.y >> 16));
            __builtin_nontemporal_store(o, (f32x4*)(ap0 + (size_t)row*SQ + kt*64 + lr*4));
        }
        if (kt < 15) {
            asm volatile("s_waitcnt vmcnt(4) lgkmcnt(0)" ::: "memory");
            __builtin_amdgcn_s_barrier();
            __builtin_amdgcn_sched_barrier(0);
        }
    }

    ushort* cp = ctx + ((size_t)b*SQ + (size_t)qt*64 + w*16)*D + hh*DK;
#pragma unroll
    for (int n = 0; n < 4; ++n)
#pragma unroll
        for (int r = 0; r < 4; ++r)
            cp[(size_t)(kg*4+r)*D + n*16 + lr] = f2bf(acc_o[n][r]);
}

// ---------------------------------------------------------------------------
// LayerNorm: wave-per-row (4 rows/block), shfl-only, no LDS/barriers,
// nontemporal y store.
// ---------------------------------------------------------------------------
__global__ __launch_bounds__(256)
void ln_k(const float* __restrict__ hbuf, const float* __restrict__ gamma,
          const float* __restrict__ beta, float* __restrict__ y)
{
    const int t = threadIdx.x;
    const int lane = t & 63;
    const int row = blockIdx.x*4 + (t >> 6);
    const f32x4* hr = (const f32x4*)(hbuf + (size_t)row * D);
    f32x4 v[4];
    float s = 0.f, sq = 0.f;
#pragma unroll
    for (int l = 0; l < 4; ++l) {
        v[l] = hr[lane + l*64];
        s  += v[l][0] + v[l][1] + v[l][2] + v[l][3];
        sq += v[l][0]*v[l][0] + v[l][1]*v[l][1] + v[l][2]*v[l][2] + v[l][3]*v[l][3];
    }
#pragma unroll
    for (int o = 32; o >= 1; o >>= 1) {
        s  += __shfl_xor(s, o, 64);
        sq += __shfl_xor(sq, o, 64);
    }
    float mu   = s * (1.0f/1024.0f);
    float var  = sq * (1.0f/1024.0f) - mu*mu;
    float rstd = rsqrtf(var + 1e-5f);
    f32x4* yp = (f32x4*)(y + (size_t)row * D);
    const f32x4* gp = (const f32x4*)gamma;
    const f32x4* bp = (const f32x4*)beta;
#pragma unroll
    for (int l = 0; l < 4; ++l) {
        f32x4 g = gp[lane + l*64], be = bp[lane + l*64];
        f32x4 o;
        o[0] = (v[l][0]-mu)*rstd*g[0] + be[0];
        o[1] = (v[l][1]-mu)*rstd*g[1] + be[1];
        o[2] = (v[l][2]-mu)*rstd*g[2] + be[2];
        o[3] = (v[l][3]-mu)*rstd*g[3] + be[3];
        __builtin_nontemporal_store(o, yp + lane + l*64);
    }
}

// ---------------------------------------------------------------------------
extern "C" void kernel_launch(void* const* d_in, const int* in_sizes, int n_in,
                              void* d_out, int out_size, void* d_ws, size_t ws_size,
                              hipStream_t stream)
{
    const float* x     = (const float*)d_in[0];
    const float* Wq    = (const float*)d_in[1];
    const float* bq    = (const float*)d_in[2];
    const float* Wk    = (const float*)d_in[3];
    const float* bk    = (const float*)d_in[4];
    const float* Wv    = (const float*)d_in[5];
    const float* bv    = (const float*)d_in[6];
    const float* Wo    = (const float*)d_in[7];
    const float* bo    = (const float*)d_in[8];
    const float* gamma = (const float*)d_in[9];
    const float* beta  = (const float*)d_in[10];

    float* y    = (float*)d_out;                     // [8,1024,1024]
    float* attn = (float*)d_out + (size_t)NROW * D;  // [8,16,1024,1024]

    const size_t SZ  = (size_t)NROW * D;             // 8M elements
    const size_t WSZ = (size_t)D * D;                // 1M elements
    ushort* ws   = (ushort*)d_ws;
    ushort* xb   = ws;                 // [8192][1024] bf16
    ushort* Wpk  = xb  + SZ;           // packed Wq|Wk|Wv [3072][1024] + Wo
    ushort* Wob  = Wpk + 3*WSZ;
    ushort* Qb   = Wob + WSZ;          // [B,H,S,DK] bf16
    ushort* Kb   = Qb  + SZ;           // [B,H,S,DK] bf16
    ushort* Vtb  = Kb  + SZ;           // [B,H,DK,SQ] bf16
    ushort* Cb   = Vtb + SZ;           // ctx [B,S,D] bf16
    float*  Hb   = (float*)(Cb + SZ);  // [8192][1024] fp32

    cvt_all<<<6144, 256, 0, stream>>>(x, Wq, Wk, Wv, Wo, xb, Wpk);

    gemm_qkv<<<1536, 256, 0, stream>>>(xb, Wpk, bq, bk, bv, Qb, Kb, Vtb);

    attn_v11<<<2048, 256, 0, stream>>>(Qb, Kb, Vtb, attn, Cb);

    gemm_o<<<512, 256, 0, stream>>>(Cb, Wob, bo, x, Hb);

    ln_k<<<2048, 256, 0, stream>>>(Hb, gamma, beta, y);
}

// Round 17
// 302.295 us; speedup vs baseline: 1.3606x; 1.0492x over previous
//
#include <hip/hip_runtime.h>
#include <math.h>

#define D 1024
#define H 16
#define DK 64
#define SQ 1024
#define NB 8
#define NROW (NB*SQ)   // 8192

typedef __attribute__((ext_vector_type(8))) short bf16x8;
typedef __attribute__((ext_vector_type(4))) float f32x4;

__device__ __forceinline__ ushort f2bf(float x){
    unsigned u = __builtin_bit_cast(unsigned, x);
    u += 0x7FFFu + ((u >> 16) & 1u);
    return (ushort)(u >> 16);
}
__device__ __forceinline__ float bf2f(ushort u){
    return __builtin_bit_cast(float, (unsigned)u << 16);
}

__device__ __forceinline__ f32x4 mfma16(bf16x8 a, bf16x8 b, f32x4 c){
    return __builtin_amdgcn_mfma_f32_16x16x32_bf16(a, b, c, 0, 0, 0);
}

__device__ __forceinline__ void gload16(const void* g, void* l){
    __builtin_amdgcn_global_load_lds(
        (const __attribute__((address_space(1))) unsigned int*)g,
        (__attribute__((address_space(3))) unsigned int*)l, 16, 0, 0);
}

__device__ __forceinline__ bf16x8 gld8(const ushort* p){
    return __builtin_bit_cast(bf16x8, *(const uint4*)p);
}

// shared fragment read for [R][64] bf16 tiles with chunk^=(row&7) swizzle
__device__ __forceinline__ bf16x8 frag_ld(const ushort* lds, int row, int chunk)
{
    uint4 v = ((const uint4*)lds)[row*8 + (chunk ^ (row & 7))];
    return __builtin_bit_cast(bf16x8, v);
}

// ---------------------------------------------------------------------------
// Fused fp32 -> bf16 conversion: x (4096 blocks) then Wq,Wk,Wv,Wo (512 each).
// ---------------------------------------------------------------------------
__global__ __launch_bounds__(256)
void cvt_all(const float* __restrict__ x,
             const float* __restrict__ Wq, const float* __restrict__ Wk,
             const float* __restrict__ Wv, const float* __restrict__ Wo,
             ushort* __restrict__ xb, ushort* __restrict__ wb_)
{
    const int bid = blockIdx.x;
    const float* s; ushort* d; size_t off;
    if (bid < 4096) { s = x; d = xb; off = (size_t)bid * 2048; }
    else {
        int r = bid - 4096;
        int wsel = r >> 9;
        if      (wsel == 0) s = Wq;
        else if (wsel == 1) s = Wk;
        else if (wsel == 2) s = Wv;
        else                s = Wo;
        d = wb_ + (size_t)wsel * 1048576;
        off = (size_t)(r & 511) * 2048;
    }
    size_t i = off + (size_t)threadIdx.x * 8;
    float4 a = *(const float4*)(s + i);
    float4 b = *(const float4*)(s + i + 4);
    ushort tmp[8] = {f2bf(a.x),f2bf(a.y),f2bf(a.z),f2bf(a.w),
                     f2bf(b.x),f2bf(b.y),f2bf(b.z),f2bf(b.w)};
    *(uint4*)(d + i) = *(uint4*)tmp;
}

// ---------------------------------------------------------------------------
// bf16 MFMA GEMM, BK=64: 128x128 tile, 4 waves, 32 MFMA per barrier pair.
// ---------------------------------------------------------------------------
__device__ __forceinline__ void stage_g64(const ushort* __restrict__ g, int ldg,
                                          ushort* lds, int t)
{
#pragma unroll
    for (int i = 0; i < 4; ++i){
        int c = i*256 + t;              // 0..1023
        int row = c >> 3, sc = c & 7;
        int gch = sc ^ (row & 7);
        gload16(g + (size_t)row*ldg + gch*8, lds + c*8);
    }
}

// Fused QKV projection: W packed [3072][1024]. grid 1536 blocks 1D,
// chunked XCD swizzle: each XCD owns 8 complete A-panels (24 blocks each).
__global__ __launch_bounds__(256)
void gemm_qkv(const ushort* __restrict__ A, const ushort* __restrict__ Wp,
              const float* __restrict__ bq, const float* __restrict__ bk,
              const float* __restrict__ bv,
              ushort* __restrict__ Qb, ushort* __restrict__ Kb,
              ushort* __restrict__ Vtb)
{
    __shared__ ushort As[8192];   // 16KB
    __shared__ ushort Bs[8192];
    const int t = threadIdx.x, lane = t & 63, w = t >> 6;
    const int wr = w >> 1, wc = w & 1, lr = lane & 15, kg = lane >> 4;
    const int swz = (blockIdx.x & 7)*192 + (blockIdx.x >> 3);
    const int bx = swz % 24, by = swz / 24;
    const int i0 = by * 128, j0 = bx * 128;
    const int section = bx >> 3;                 // 0=Q 1=K 2=V
    const ushort* Ab = A  + (size_t)i0 * 1024;
    const ushort* Wb = Wp + (size_t)j0 * 1024;
    const float* bias = (section == 0) ? bq : (section == 1) ? bk : bv;
    ushort* outp      = (section == 0) ? Qb : (section == 1) ? Kb : Vtb;

    f32x4 acc[4][4];
#pragma unroll
    for (int m = 0; m < 4; ++m)
#pragma unroll
        for (int n = 0; n < 4; ++n) acc[m][n] = (f32x4){0.f,0.f,0.f,0.f};

    for (int k0 = 0; k0 < 1024; k0 += 64){
        __syncthreads();
        stage_g64(Ab + k0, 1024, As, t);
        stage_g64(Wb + k0, 1024, Bs, t);
        __syncthreads();
#pragma unroll
        for (int ks = 0; ks < 2; ++ks){
            bf16x8 af[4], bfr[4];
#pragma unroll
            for (int m = 0; m < 4; ++m) af[m]  = frag_ld(As, wr*64 + m*16 + lr, ks*4 + kg);
#pragma unroll
            for (int n = 0; n < 4; ++n) bfr[n] = frag_ld(Bs, wc*64 + n*16 + lr, ks*4 + kg);
#pragma unroll
            for (int m = 0; m < 4; ++m)
#pragma unroll
                for (int n = 0; n < 4; ++n)
                    acc[m][n] = mfma16(af[m], bfr[n], acc[m][n]);
        }
    }

#pragma unroll
    for (int m = 0; m < 4; ++m){
        int rt = i0 + wr*64 + m*16 + kg*4;
#pragma unroll
        for (int n = 0; n < 4; ++n){
            int jc = ((j0 + wc*64 + n*16 + lr) & 1023);
            float bj = bias[jc];
            int hh = jc >> 6, dd = jc & 63;
#pragma unroll
            for (int j = 0; j < 4; ++j){
                int i = rt + j;
                int b = i >> 10, s = i & 1023;
                float v = acc[m][n][j] + bj;
                size_t idx = (section < 2)
                    ? ((((size_t)b*H + hh)*SQ + s)*DK + dd)
                    : ((((size_t)b*H + hh)*DK + dd)*SQ + s);
                outp[idx] = f2bf(v);
            }
        }
    }
}

// Output projection: fp32 out + residual. 1D grid 512, chunked XCD swizzle.
__global__ __launch_bounds__(256)
void gemm_o(const ushort* __restrict__ A, const ushort* __restrict__ W,
            const float* __restrict__ bias, const float* __restrict__ resid,
            float* __restrict__ out)
{
    __shared__ ushort As[8192];
    __shared__ ushort Bs[8192];
    const int t = threadIdx.x, lane = t & 63, w = t >> 6;
    const int wr = w >> 1, wc = w & 1, lr = lane & 15, kg = lane >> 4;
    const int swz = (blockIdx.x & 7)*64 + (blockIdx.x >> 3);
    const int bx = swz & 7, by = swz >> 3;
    const int i0 = by * 128, j0 = bx * 128;
    const ushort* Ab = A + (size_t)i0 * 1024;
    const ushort* Wb = W + (size_t)j0 * 1024;

    f32x4 acc[4][4];
#pragma unroll
    for (int m = 0; m < 4; ++m)
#pragma unroll
        for (int n = 0; n < 4; ++n) acc[m][n] = (f32x4){0.f,0.f,0.f,0.f};

    for (int k0 = 0; k0 < 1024; k0 += 64){
        __syncthreads();
        stage_g64(Ab + k0, 1024, As, t);
        stage_g64(Wb + k0, 1024, Bs, t);
        __syncthreads();
#pragma unroll
        for (int ks = 0; ks < 2; ++ks){
            bf16x8 af[4], bfr[4];
#pragma unroll
            for (int m = 0; m < 4; ++m) af[m]  = frag_ld(As, wr*64 + m*16 + lr, ks*4 + kg);
#pragma unroll
            for (int n = 0; n < 4; ++n) bfr[n] = frag_ld(Bs, wc*64 + n*16 + lr, ks*4 + kg);
#pragma unroll
            for (int m = 0; m < 4; ++m)
#pragma unroll
                for (int n = 0; n < 4; ++n)
                    acc[m][n] = mfma16(af[m], bfr[n], acc[m][n]);
        }
    }

#pragma unroll
    for (int m = 0; m < 4; ++m){
        int rt = i0 + wr*64 + m*16 + kg*4;
#pragma unroll
        for (int n = 0; n < 4; ++n){
            int ct = j0 + wc*64 + n*16 + lr;
            float bj = bias[ct];
#pragma unroll
            for (int j = 0; j < 4; ++j){
                int i = rt + j;
                out[(size_t)i*1024 + ct] = acc[m][n][j] + bj + resid[(size_t)i*1024 + ct];
            }
        }
    }
}

// ---------------------------------------------------------------------------
// Flash attention v11 (r13 best): two-pass no-max, KV dbuf, counted-vmcnt
// pass-2 barriers, NONTEMPORAL float4 attn stores. No setprio (r16: -15us).
// ---------------------------------------------------------------------------
__device__ __forceinline__ void stage64x64(const ushort* __restrict__ g, int ldg,
                                           ushort* lds, int t)
{
#pragma unroll
    for (int i = 0; i < 2; ++i){
        int c = i*256 + t;
        int row = c >> 3, sc = c & 7;
        int gch = sc ^ (row & 7);
        gload16(g + (size_t)row*ldg + gch*8, lds + c*8);
    }
}

__global__ __launch_bounds__(256)
void attn_v11(const ushort* __restrict__ Q, const ushort* __restrict__ K,
              const ushort* __restrict__ Vt, float* __restrict__ attn_out,
              ushort* __restrict__ ctx)
{
    __shared__ ushort KV[2][8192];   // [buf][ K 4096 | V 4096 ] ushorts
    __shared__ ushort Ps[4][1024];   // per-wave 16x64 normalized P (bf16)

    const int t    = threadIdx.x;
    const int lane = t & 63;
    const int w    = t >> 6;
    const int lr   = lane & 15, kg = lane >> 4;
    const int bid  = blockIdx.x;
    const int qt   = bid >> 7, bh = bid & 127;
    const int b    = bh >> 4, hh = bh & 15;
    const size_t base = (size_t)bh * SQ * DK;

    bf16x8 qf[2];
    {
        const ushort* qrow = Q + base + (size_t)(qt*64 + w*16 + lr) * DK + kg*8;
        qf[0] = gld8(qrow);
        qf[1] = gld8(qrow + 32);
    }

    const float CEXP = 0.18033688011112042f;   // log2(e)/8

    // ---- pass 1: row sums ----
    float lsum[4] = {0.f, 0.f, 0.f, 0.f};
    stage64x64(K + base, DK, KV[0], t);
    for (int kt = 0; kt < 16; ++kt) {
        const int cur = kt & 1;
        __syncthreads();
        if (kt < 15)
            stage64x64(K + base + (size_t)(kt+1)*64*DK, DK, KV[cur^1], t);
        const ushort* Ks = KV[cur];
#pragma unroll
        for (int n = 0; n < 4; ++n) {
            f32x4 z = {0.f,0.f,0.f,0.f};
            z = mfma16(qf[0], frag_ld(Ks, n*16+lr, kg),   z);
            z = mfma16(qf[1], frag_ld(Ks, n*16+lr, 4+kg), z);
#pragma unroll
            for (int r = 0; r < 4; ++r)
                lsum[r] += exp2f(z[r] * CEXP);
        }
    }
    float invl[4];
#pragma unroll
    for (int r = 0; r < 4; ++r) {
        float s = lsum[r];
#pragma unroll
        for (int msk = 1; msk < 16; msk <<= 1) s += __shfl_xor(s, msk, 64);
        invl[r] = 1.0f / s;
    }

    // ---- pass 2: recompute, write normalized P (nontemporal), PV ----
    f32x4 acc_o[4];
#pragma unroll
    for (int n = 0; n < 4; ++n) acc_o[n] = (f32x4){0.f,0.f,0.f,0.f};

    float* ap0 = attn_out + ((size_t)bh*SQ + (size_t)qt*64 + w*16)*SQ;
    ushort* pw = &Ps[w][0];

    stage64x64(K  + base, DK, KV[0],        t);
    stage64x64(Vt + base, SQ, KV[0] + 4096, t);
    asm volatile("s_waitcnt vmcnt(0) lgkmcnt(0)" ::: "memory");
    __builtin_amdgcn_s_barrier();
    __builtin_amdgcn_sched_barrier(0);

    for (int kt = 0; kt < 16; ++kt) {
        const int cur = kt & 1;
        if (kt < 15) {
            stage64x64(K  + base + (size_t)(kt+1)*64*DK, DK, KV[cur^1],        t);
            stage64x64(Vt + base + (size_t)(kt+1)*64,    SQ, KV[cur^1] + 4096, t);
        }
        const ushort* Ks = KV[cur];
        const ushort* Vs = KV[cur] + 4096;

        f32x4 sc[4];
#pragma unroll
        for (int n = 0; n < 4; ++n) {
            f32x4 z = {0.f,0.f,0.f,0.f};
            z = mfma16(qf[0], frag_ld(Ks, n*16+lr, kg),   z);
            z = mfma16(qf[1], frag_ld(Ks, n*16+lr, 4+kg), z);
            sc[n] = z;
        }
#pragma unroll
        for (int n = 0; n < 4; ++n) {
#pragma unroll
            for (int r = 0; r < 4; ++r) {
                float p = exp2f(sc[n][r] * CEXP) * invl[r];
                int row = kg*4 + r, col = n*16 + lr;
                pw[row*64 + ((col>>3) ^ (row&7))*8 + (col&7)] = f2bf(p);
            }
        }
        bf16x8 a0 = frag_ld(pw, lr, kg);
        bf16x8 a1 = frag_ld(pw, lr, 4+kg);
#pragma unroll
        for (int n = 0; n < 4; ++n) {
            acc_o[n] = mfma16(a0, frag_ld(Vs, n*16+lr, kg),   acc_o[n]);
            acc_o[n] = mfma16(a1, frag_ld(Vs, n*16+lr, 4+kg), acc_o[n]);
        }
        // nontemporal f32x4 attn writeout (bypass L2 allocation)
#pragma unroll
        for (int rr = 0; rr < 4; ++rr) {
            int row = kg*4 + rr;
            int cidx = row*64 + ((lr>>1) ^ (row&7))*8 + (lr&1)*4;
            uint2 pk = *(const uint2*)(pw + cidx);
            f32x4 o;
            o[0] = bf2f((ushort)(pk.x & 0xFFFF));
            o[1] = bf2f((ushort)(pk.x >> 16));
            o[2] = bf2f((ushort)(pk.y & 0xFFFF));
            o[3] = bf2f((ushort)(pk.y >> 16));
            __builtin_nontemporal_store(o, (f32x4*)(ap0 + (size_t)row*SQ + kt*64 + lr*4));
        }
        if (kt < 15) {
            asm volatile("s_waitcnt vmcnt(4) lgkmcnt(0)" ::: "memory");
            __builtin_amdgcn_s_barrier();
            __builtin_amdgcn_sched_barrier(0);
        }
    }

    ushort* cp = ctx + ((size_t)b*SQ + (size_t)qt*64 + w*16)*D + hh*DK;
#pragma unroll
    for (int n = 0; n < 4; ++n)
#pragma unroll
        for (int r = 0; r < 4; ++r)
            cp[(size_t)(kg*4+r)*D + n*16 + lr] = f2bf(acc_o[n][r]);
}

// ---------------------------------------------------------------------------
// LayerNorm: wave-per-row (4 rows/block), shfl-only, no LDS/barriers,
// nontemporal y store.
// ---------------------------------------------------------------------------
__global__ __launch_bounds__(256)
void ln_k(const float* __restrict__ hbuf, const float* __restrict__ gamma,
          const float* __restrict__ beta, float* __restrict__ y)
{
    const int t = threadIdx.x;
    const int lane = t & 63;
    const int row = blockIdx.x*4 + (t >> 6);
    const f32x4* hr = (const f32x4*)(hbuf + (size_t)row * D);
    f32x4 v[4];
    float s = 0.f, sq = 0.f;
#pragma unroll
    for (int l = 0; l < 4; ++l) {
        v[l] = hr[lane + l*64];
        s  += v[l][0] + v[l][1] + v[l][2] + v[l][3];
        sq += v[l][0]*v[l][0] + v[l][1]*v[l][1] + v[l][2]*v[l][2] + v[l][3]*v[l][3];
    }
#pragma unroll
    for (int o = 32; o >= 1; o >>= 1) {
        s  += __shfl_xor(s, o, 64);
        sq += __shfl_xor(sq, o, 64);
    }
    float mu   = s * (1.0f/1024.0f);
    float var  = sq * (1.0f/1024.0f) - mu*mu;
    float rstd = rsqrtf(var + 1e-5f);
    f32x4* yp = (f32x4*)(y + (size_t)row * D);
    const f32x4* gp = (const f32x4*)gamma;
    const f32x4* bp = (const f32x4*)beta;
#pragma unroll
    for (int l = 0; l < 4; ++l) {
        f32x4 g = gp[lane + l*64], be = bp[lane + l*64];
        f32x4 o;
        o[0] = (v[l][0]-mu)*rstd*g[0] + be[0];
        o[1] = (v[l][1]-mu)*rstd*g[1] + be[1];
        o[2] = (v[l][2]-mu)*rstd*g[2] + be[2];
        o[3] = (v[l][3]-mu)*rstd*g[3] + be[3];
        __builtin_nontemporal_store(o, yp + lane + l*64);
    }
}

// ---------------------------------------------------------------------------
extern "C" void kernel_launch(void* const* d_in, const int* in_sizes, int n_in,
                              void* d_out, int out_size, void* d_ws, size_t ws_size,
                              hipStream_t stream)
{
    const float* x     = (const float*)d_in[0];
    const float* Wq    = (const float*)d_in[1];
    const float* bq    = (const float*)d_in[2];
    const float* Wk    = (const float*)d_in[3];
    const float* bk    = (const float*)d_in[4];
    const float* Wv    = (const float*)d_in[5];
    const float* bv    = (const float*)d_in[6];
    const float* Wo    = (const float*)d_in[7];
    const float* bo    = (const float*)d_in[8];
    const float* gamma = (const float*)d_in[9];
    const float* beta  = (const float*)d_in[10];

    float* y    = (float*)d_out;                     // [8,1024,1024]
    float* attn = (float*)d_out + (size_t)NROW * D;  // [8,16,1024,1024]

    const size_t SZ  = (size_t)NROW * D;             // 8M elements
    const size_t WSZ = (size_t)D * D;                // 1M elements
    ushort* ws   = (ushort*)d_ws;
    ushort* xb   = ws;                 // [8192][1024] bf16
    ushort* Wpk  = xb  + SZ;           // packed Wq|Wk|Wv [3072][1024] + Wo
    ushort* Wob  = Wpk + 3*WSZ;
    ushort* Qb   = Wob + WSZ;          // [B,H,S,DK] bf16
    ushort* Kb   = Qb  + SZ;           // [B,H,S,DK] bf16
    ushort* Vtb  = Kb  + SZ;           // [B,H,DK,SQ] bf16
    ushort* Cb   = Vtb + SZ;           // ctx [B,S,D] bf16
    float*  Hb   = (float*)(Cb + SZ);  // [8192][1024] fp32

    cvt_all<<<6144, 256, 0, stream>>>(x, Wq, Wk, Wv, Wo, xb, Wpk);

    gemm_qkv<<<1536, 256, 0, stream>>>(xb, Wpk, bq, bk, bv, Qb, Kb, Vtb);

    attn_v11<<<2048, 256, 0, stream>>>(Qb, Kb, Vtb, attn, Cb);

    gemm_o<<<512, 256, 0, stream>>>(Cb, Wob, bo, x, Hb);

    ln_k<<<2048, 256, 0, stream>>>(Hb, gamma, beta, y);
}